// Round 3
// baseline (2899.328 us; speedup 1.0000x reference)
//
#include <hip/hip_runtime.h>

constexpr int G  = 8;
constexpr int NN = 50000;
constexpr int EE = 800000;
constexpr int F  = 128;

typedef float float4_t __attribute__((ext_vector_type(4)));

// ---------------- graph structure build ----------------
// edge_index is int32 on device. Layout [G, 2, E].

__global__ __launch_bounds__(256) void deg_kernel(const int* __restrict__ edges,
                                                  int* __restrict__ deg, int gbase) {
  int gw = blockIdx.y;
  size_t ebase = ((size_t)(gbase + gw) * 2 + 1) * EE;   // dst half
  int e = blockIdx.x * 256 + threadIdx.x;               // grid.x*256 == EE exactly
  int dst = edges[ebase + e];
  atomicAdd(&deg[gw * NN + dst], 1);
}

// one block per (chunk-local) graph: exclusive scan of deg -> row_off, dinv, reset deg->cursor
__global__ __launch_bounds__(1024) void scan_kernel(int* __restrict__ deg, int* __restrict__ row_off,
                                                    float* __restrict__ dinv) {
  int gw  = blockIdx.x;
  int tid = threadIdx.x;
  int lane = tid & 63, wid = tid >> 6;
  __shared__ int wsum[16];
  __shared__ int carry_s;
  if (tid == 0) carry_s = 0;
  __syncthreads();
  int*   dg = deg + gw * NN;
  int*   ro = row_off + gw * (NN + 1);
  float* dv = dinv + gw * NN;
  for (int base = 0; base < NN; base += 1024) {
    int i = base + tid;
    int v = 0;
    if (i < NN) {
      v = dg[i];
      dv[i] = rsqrtf((float)v + 1.0f);
      dg[i] = 0;  // becomes cursor for fill_kernel
    }
    int incl = v;
    #pragma unroll
    for (int off = 1; off < 64; off <<= 1) {
      int t = __shfl_up(incl, off);
      if (lane >= off) incl += t;
    }
    if (lane == 63) wsum[wid] = incl;
    __syncthreads();
    if (tid == 0) {
      int s = 0;
      #pragma unroll
      for (int w = 0; w < 16; ++w) { int t = wsum[w]; wsum[w] = s; s += t; }
    }
    __syncthreads();
    int excl = carry_s + wsum[wid] + (incl - v);
    if (i < NN) ro[i] = excl;
    __syncthreads();
    if (tid == 1023) carry_s = excl + v;
    __syncthreads();
  }
  if (tid == 0) ro[NN] = carry_s;          // == EE
}

__global__ __launch_bounds__(256) void fill_kernel(const int* __restrict__ edges,
                                                   int* __restrict__ cursor, const int* __restrict__ row_off,
                                                   int* __restrict__ csr, int gbase) {
  int gw = blockIdx.y;
  size_t ebase = (size_t)(gbase + gw) * 2 * EE;
  int e = blockIdx.x * 256 + threadIdx.x;
  int src = edges[ebase + e];
  int dst = edges[ebase + EE + e];
  int slot = atomicAdd(&cursor[gw * NN + dst], 1);
  csr[(size_t)gw * EE + row_off[gw * (NN + 1) + dst] + slot] = src;
}

// ---------------- per-layer compute (per-graph dispatches) ----------------

// h1 = hg @ W. 64-row x 128-col tile, 256 threads, K split 2x64.
// LDS 48KB -> 3 blocks/CU (12 waves/CU). a-reads are broadcast; w-reads lane-pair shared.
__global__ __launch_bounds__(256, 3) void gemm_kernel(const float* __restrict__ hg,
                                                      const float* __restrict__ W,
                                                      float* __restrict__ h1) {
  __shared__ float Al[64][64];
  __shared__ float Wl[64][128];
  int row0 = blockIdx.x * 64;
  int t = threadIdx.x;
  int cseg = t & 31, rb = t >> 5;   // cseg: 4-col group of 32, rb in [0,8)
  float4_t acc[8];
  #pragma unroll
  for (int i = 0; i < 8; ++i) acc[i] = (float4_t){0.f, 0.f, 0.f, 0.f};

  for (int ks = 0; ks < F; ks += 64) {
    __syncthreads();   // protect LDS reuse from previous half-K reads
    #pragma unroll
    for (int p = 0; p < 4; ++p) {   // Al: 64x64 floats, 4 float4/thread
      int idx = p * 256 + t;
      int r = idx >> 4, c = (idx & 15) * 4;
      int grow = row0 + r;
      float4_t v = {0.f, 0.f, 0.f, 0.f};
      if (grow < NN) v = *(const float4_t*)(hg + (size_t)grow * F + ks + c);
      *(float4_t*)(&Al[r][c]) = v;
    }
    #pragma unroll
    for (int p = 0; p < 8; ++p) {   // Wl: 64x128 floats, 8 float4/thread
      int idx = p * 256 + t;
      int k = idx >> 5, c = (idx & 31) * 4;
      *(float4_t*)(&Wl[k][c]) = *(const float4_t*)(W + (size_t)(ks + k) * F + c);
    }
    __syncthreads();
    #pragma unroll 4
    for (int k4 = 0; k4 < 16; ++k4) {
      float4_t w0 = *(const float4_t*)(&Wl[k4 * 4 + 0][cseg * 4]);
      float4_t w1 = *(const float4_t*)(&Wl[k4 * 4 + 1][cseg * 4]);
      float4_t w2 = *(const float4_t*)(&Wl[k4 * 4 + 2][cseg * 4]);
      float4_t w3 = *(const float4_t*)(&Wl[k4 * 4 + 3][cseg * 4]);
      #pragma unroll
      for (int i = 0; i < 8; ++i) {
        float4_t a4 = *(const float4_t*)(&Al[rb + 8 * i][k4 * 4]);  // broadcast
        acc[i] += a4[0] * w0;
        acc[i] += a4[1] * w1;
        acc[i] += a4[2] * w2;
        acc[i] += a4[3] * w3;
      }
    }
  }
  #pragma unroll
  for (int i = 0; i < 8; ++i) {
    int grow = row0 + rb + 8 * i;
    if (grow < NN) *(float4_t*)(h1 + (size_t)grow * F + cseg * 4) = acc[i];
  }
}

// out[n] = relu(dinv[n]*(h1[n]*dinv[n] + sum_src h1[src]*dinv[src]) + b)
// 32 lanes per node (float4/lane), 8 nodes per 256-thread block; per-graph dispatch
__global__ __launch_bounds__(256) void agg_kernel(const float* __restrict__ h1, const int* __restrict__ cs,
                                                  const int* __restrict__ ro, const float* __restrict__ dv,
                                                  const float* __restrict__ bias, float* __restrict__ outg) {
  int grp = threadIdx.x >> 5, lane = threadIdx.x & 31;
  int node = blockIdx.x * 8 + grp;
  if (node >= NN) return;
  int e0 = ro[node];
  int e1 = ro[node + 1];
  float di = dv[node];
  float4_t acc0 = *(const float4_t*)(h1 + (size_t)node * F + lane * 4) * di;  // self-loop
  float4_t acc1 = {0.f, 0.f, 0.f, 0.f};
  int e = e0;
  for (; e + 1 < e1; e += 2) {
    int s0 = cs[e], s1 = cs[e + 1];
    float d0 = dv[s0], d1 = dv[s1];
    float4_t v0 = *(const float4_t*)(h1 + (size_t)s0 * F + lane * 4);
    float4_t v1 = *(const float4_t*)(h1 + (size_t)s1 * F + lane * 4);
    acc0 += v0 * d0;
    acc1 += v1 * d1;
  }
  if (e < e1) {
    int s = cs[e];
    acc0 += *(const float4_t*)(h1 + (size_t)s * F + lane * 4) * dv[s];
  }
  float4_t bb = *(const float4_t*)(bias + lane * 4);
  float4_t o;
  #pragma unroll
  for (int j = 0; j < 4; ++j) o[j] = fmaxf(fmaf(acc0[j] + acc1[j], di, bb[j]), 0.f);
  *(float4_t*)(outg + (size_t)node * F + lane * 4) = o;
}

// ---------------- host launch ----------------

extern "C" void kernel_launch(void* const* d_in, const int* in_sizes, int n_in,
                              void* d_out, int out_size, void* d_ws, size_t ws_size,
                              hipStream_t stream) {
  const float* x     = (const float*)d_in[0];
  const int*   edges = (const int*)d_in[1];
  const float* Ws[3] = {(const float*)d_in[2], (const float*)d_in[4], (const float*)d_in[6]};
  const float* bs[3] = {(const float*)d_in[3], (const float*)d_in[5], (const float*)d_in[7]};
  float* out = (float*)d_out;

  size_t sz_h1  = (size_t)NN * F * 4;     // 25.6 MB (single graph, reused)
  size_t sz_csr = (size_t)EE * 4;
  size_t sz_deg = (size_t)NN * 4;
  size_t sz_dv  = (size_t)NN * 4;
  size_t sz_ro  = (size_t)(NN + 1) * 4;
  size_t per_b  = sz_csr + sz_deg + sz_dv + sz_ro;  // ~3.6 MB per graph (build)

  int CB = (int)((ws_size > sz_h1 ? ws_size - sz_h1 : 0) / per_b);
  if (CB < 1) CB = 1;
  if (CB > G) CB = G;

  char* p = (char*)d_ws;
  float* h1      = (float*)p;  p += sz_h1;
  int*   csr     = (int*)p;    p += sz_csr * CB;
  int*   deg     = (int*)p;    p += sz_deg * CB;   // doubles as cursor
  float* dinv    = (float*)p;  p += sz_dv  * CB;
  int*   row_off = (int*)p;

  for (int gb = 0; gb < G; gb += CB) {
    int Cg = G - gb < CB ? G - gb : CB;
    hipMemsetAsync(deg, 0, (size_t)Cg * NN * 4, stream);
    deg_kernel <<<dim3(EE / 256, Cg), 256, 0, stream>>>(edges, deg, gb);
    scan_kernel<<<Cg, 1024, 0, stream>>>(deg, row_off, dinv);
    fill_kernel<<<dim3(EE / 256, Cg), 256, 0, stream>>>(edges, deg, row_off, csr, gb);
    for (int gw = 0; gw < Cg; ++gw) {
      int g = gb + gw;
      float* outg = out + (size_t)g * NN * F;
      for (int l = 0; l < 3; ++l) {
        const float* hin = (l == 0) ? x + (size_t)g * NN * F : outg;
        gemm_kernel<<<(NN + 63) / 64, 256, 0, stream>>>(hin, Ws[l], h1);
        agg_kernel <<<(NN + 7) / 8, 256, 0, stream>>>(h1, csr + (size_t)gw * EE,
                                                      row_off + (size_t)gw * (NN + 1),
                                                      dinv + (size_t)gw * NN, bs[l], outg);
      }
    }
  }
}